// Round 2
// baseline (118.168 us; speedup 1.0000x reference)
//
#include <hip/hip_runtime.h>

// IndexedLinear: out[z, s*V:(s+1)*V] = coeff[s] * x[z, s*U:(s+1)*U] @ W[seg(z), s]
// S=8, U=V=32, C=32 segments, Z=65536. HBM-bound: ~130 MiB -> ~21us @ 6.3TB/s.
// R7 == R6 resubmit (both prior rounds died to infra, zero measurements).
// R6 (from R5's 117.9us): persistent 4-tile blocks + counted-vmcnt pipeline.
//  - grid 512, each block owns TPB=4 consecutive 32-row z-tiles; B fragments
//    (W slice, coeff folded) converted ONCE per segment-change (1x/block here)
//    instead of per tile: removes 32 L2 loads + ~100 VALU per wave-tile.
//  - double-buffered LDS (2x32KiB): tile t+1 DMA'd via global_load_lds while
//    tile t computes. Raw s_barrier + `s_waitcnt vmcnt(8)` (never 0 mid-loop)
//    replaces __syncthreads' full vmcnt(0) drain -> HBM latency hidden (T3/T4).
//  - A-conversion via v_cvt_pk_bf16_f32 (bit-identical RNE to manual f2bf,
//    1 inst per 2 floats instead of ~3 per float).
//  - LDS layout, xidx swizzle, MFMA B-frag/C/D store maps, fp32 boundary
//    fallback all carried over verified from R5 (fallback reads XL[bsel]).
// Audited hang-free: barrier counts match on both paths; vmcnt(8) leaves
// exactly the 8 prefetch DMAs in flight; buffer reuse gated by barrier.

constexpr int S = 8, U = 32, V = 32, C = 32, Z = 65536;
constexpr int SU = S * U;   // 256
constexpr int SV = S * V;   // 256
constexpr int NT = 256;     // 4 waves
constexpr int BZ = 32;      // z rows per tile
constexpr int TPB = 4;      // tiles per block -> grid = 512, 2 blocks/CU (LDS)

typedef float    f4     __attribute__((ext_vector_type(4)));
typedef float    f32x16 __attribute__((ext_vector_type(16)));
typedef short    bf16x8 __attribute__((ext_vector_type(8)));
typedef unsigned u32x4  __attribute__((ext_vector_type(4)));

typedef const __attribute__((address_space(1))) unsigned gu32;
typedef __attribute__((address_space(3))) unsigned lu32;

__device__ __forceinline__ short f2bf(float f) {
  unsigned u = __builtin_bit_cast(unsigned, f);
  u = (u + 0x7FFFu + ((u >> 16) & 1u)) >> 16;
  return (short)u;
}

// packed RNE f32x2 -> bf16x2 (low = lo, high = hi)
__device__ __forceinline__ unsigned cvtpk(float lo, float hi) {
  unsigned r;
  asm("v_cvt_pk_bf16_f32 %0, %1, %2" : "=v"(r) : "v"(lo), "v"(hi));
  return r;
}

// LDS f4-slot of logical (row m in [0,32), 16B-chunk c in [0,64))
__device__ __forceinline__ int xidx(int m, int c) {
  return ((m >> 3) << 9) + ((c >> 3) << 6) + ((c & 7) << 3) + (m & 7);
}

__global__ __launch_bounds__(NT) void IndexedLinear_kernel(
    const float* __restrict__ W_all,   // (C, S*U*V)
    const float* __restrict__ X,       // (Z, S*U)
    const int*   __restrict__ counts,  // (C,)
    const float* __restrict__ coeff,   // (S,)
    float*       __restrict__ out)     // (Z, S*V)
{
  const int tid  = threadIdx.x;
  const int lane = tid & 63;
  const int w    = tid >> 6;
  const int zb   = blockIdx.x * (BZ * TPB);

  __shared__ f4 XL[2][BZ * 64];  // 2 x 32 KiB double buffer

  // ---- segment exclusive-prefix scan (once per block) ----
  int cnt = (lane < C) ? counts[lane] : 0;
  int inc = cnt;
  #pragma unroll
  for (int d = 1; d < 32; d <<= 1) {
    int o = __shfl_up(inc, d, 64);
    if (lane >= d) inc += o;
  }
  const int exc = inc - cnt;

  const int m  = lane & 31;   // A row / B col / C col
  const int h  = lane >> 5;   // k-half
  const int s0 = 2 * w;

  // ---- stage tile 0 -> buf 0 (8x global_load_lds dwordx4 per wave) ----
  {
    const char* gb = (const char*)X
        + (size_t)(zb + 8 * w + (lane & 7)) * (SU * 4) + (lane >> 3) * 16;
    #pragma unroll
    for (int k = 0; k < 8; ++k)
      __builtin_amdgcn_global_load_lds((gu32*)(gb + k * 128),
                                       (lu32*)&XL[0][(8 * w + k) * 64], 16, 0, 0);
  }

  int curseg = -1;
  bf16x8 b1[2], b2[2];

  for (int t = 0; t < TPB; ++t) {
    const int z0   = zb + t * BZ;
    const int bsel = t & 1;

    // segment ids for this tile (cheap; overlaps in-flight DMA)
    const unsigned long long ma = __ballot(lane < C && exc <= z0);
    const unsigned long long mb = __ballot(lane < C && exc <= z0 + BZ - 1);
    const int segA = __popcll(ma) - 1;
    const int segB = __popcll(mb) - 1;
    const bool uni = (segA == segB);

    // ---- B fragments: reload only on segment change (before prefetch issue,
    //      so the compiler's wait for these L2 loads can't drain the prefetch)
    if (uni && segA != curseg) {
      curseg = segA;
      const float* wseg = W_all + (size_t)segA * (S * U * V);
      #pragma unroll
      for (int tt = 0; tt < 2; ++tt) {
        const int s = s0 + tt;
        const float cs = coeff[s];
        const float* wb = wseg + s * (U * V);
        #pragma unroll
        for (int j = 0; j < 8; ++j)
          b1[tt][j] = f2bf(wb[(8 * h + j) * V + m] * cs);
        #pragma unroll
        for (int j = 0; j < 8; ++j)
          b2[tt][j] = f2bf(wb[(16 + 8 * h + j) * V + m] * cs);
      }
    }

    // ---- prefetch tile t+1 into the other buffer, then counted wait ----
    if (t + 1 < TPB) {
      const char* gb = (const char*)X
          + (size_t)(z0 + BZ + 8 * w + (lane & 7)) * (SU * 4) + (lane >> 3) * 16;
      #pragma unroll
      for (int k = 0; k < 8; ++k)
        __builtin_amdgcn_global_load_lds((gu32*)(gb + k * 128),
                                         (lu32*)&XL[bsel ^ 1][(8 * w + k) * 64],
                                         16, 0, 0);
      asm volatile("s_waitcnt vmcnt(8)" ::: "memory");  // tile t done, t+1 in flight
    } else {
      asm volatile("s_waitcnt vmcnt(0)" ::: "memory");  // last tile: drain
    }
    __builtin_amdgcn_s_barrier();
    asm volatile("" ::: "memory");

    if (uni) {
      #pragma unroll
      for (int tt = 0; tt < 2; ++tt) {
        const int s = s0 + tt;
        // A fragments from swizzled LDS (4x ds_read_b128)
        const f4 xa = XL[bsel][xidx(m, s * 8 + 2 * h)];
        const f4 xb = XL[bsel][xidx(m, s * 8 + 2 * h + 1)];
        const f4 xc = XL[bsel][xidx(m, s * 8 + 4 + 2 * h)];
        const f4 xd = XL[bsel][xidx(m, s * 8 + 4 + 2 * h + 1)];
        u32x4 pa, pb;
        pa[0] = cvtpk(xa[0], xa[1]); pa[1] = cvtpk(xa[2], xa[3]);
        pa[2] = cvtpk(xb[0], xb[1]); pa[3] = cvtpk(xb[2], xb[3]);
        pb[0] = cvtpk(xc[0], xc[1]); pb[1] = cvtpk(xc[2], xc[3]);
        pb[2] = cvtpk(xd[0], xd[1]); pb[3] = cvtpk(xd[2], xd[3]);
        const bf16x8 a1 = __builtin_bit_cast(bf16x8, pa);
        const bf16x8 a2 = __builtin_bit_cast(bf16x8, pb);
        f32x16 acc = {};
        acc = __builtin_amdgcn_mfma_f32_32x32x16_bf16(a1, b1[tt], acc, 0, 0, 0);
        acc = __builtin_amdgcn_mfma_f32_32x32x16_bf16(a2, b2[tt], acc, 0, 0, 0);

        float* ob = out + (size_t)z0 * SV + s * V + m;
        #pragma unroll
        for (int r = 0; r < 16; ++r) {
          const int row = (r & 3) + 8 * (r >> 2) + 4 * h;
          __builtin_nontemporal_store(acc[r], ob + (size_t)row * SV);
        }
      }
    } else {
      // ---- fallback: tile crosses a segment boundary (fp32 exact) ----
      const int zz = z0 + m;
      int sg = 0;
      #pragma unroll 1
      for (int i = 1; i < C; ++i) {
        const int pi = __shfl(exc, i, 64);
        if (pi <= zz) sg = i;
      }
      #pragma unroll 1
      for (int tt = 0; tt < 2; ++tt) {
        const int s = s0 + tt;
        const float cs = coeff[s];
        const float* wr = W_all + (size_t)sg * (S * U * V) + s * (U * V) + 16 * h;
        float accv[16] = {};
        #pragma unroll 1
        for (int cq = 0; cq < 8; ++cq) {
          const f4 xv = XL[bsel][xidx(m, s * 8 + cq)];
          #pragma unroll
          for (int ii = 0; ii < 4; ++ii) {
            const int u = cq * 4 + ii;
            const float xu = xv[ii];
            #pragma unroll
            for (int j = 0; j < 16; ++j) accv[j] += xu * wr[u * V + j];
          }
        }
        float* ob = out + (size_t)zz * SV + s * V + 16 * h;
        #pragma unroll
        for (int j = 0; j < 16; ++j) ob[j] = accv[j] * cs;
      }
    }

    // all LDS reads of buf[bsel] are data-complete before any wave passes this
    // barrier (results consumed by MFMA/stores above) -> safe to overwrite next
    asm volatile("" ::: "memory");
    __builtin_amdgcn_s_barrier();
  }
}

extern "C" void kernel_launch(void* const* d_in, const int* in_sizes, int n_in,
                              void* d_out, int out_size, void* d_ws, size_t ws_size,
                              hipStream_t stream) {
  const float* input1       = (const float*)d_in[0];  // (C, S*U*V)
  const float* input2       = (const float*)d_in[1];  // (Z, S*U)
  const int*   counts       = (const int*)d_in[2];    // (C,)
  const float* coefficients = (const float*)d_in[3];  // (S,)
  float*       out          = (float*)d_out;          // (Z, S*V)

  const int grid = Z / (BZ * TPB);  // 512 blocks x 4 tiles, all 8 s per block
  IndexedLinear_kernel<<<grid, NT, 0, stream>>>(input1, input2, counts,
                                                coefficients, out);
}